// Round 11
// baseline (96.934 us; speedup 1.0000x reference)
//
#include <hip/hip_runtime.h>

// DeformConv2D b=4,c=128,H=W=64,outc=128,KS=3,PAD=1,N=9
// 2-launch pipeline (mode 3):
//   prep   : wfrag32 + xpose + desc + zero(out), fused, branch on blockIdx
//   splitk : grid 1536 = b4*i64*jh2*kh3 (XCD-swizzled), block = 32px x 128o,
//            256 thr (4 waves; wave = 32o x 32px via mfma_f32_32x32x16_bf16).
//            Staging: quarter-wave dwordx4 gathers. Epilogue: atomicAdd.
// Fallback (mode<=2): round-5 fused kernel (verified, 16x16x32 path).

typedef __bf16  v8bf16 __attribute__((ext_vector_type(8)));
typedef __bf16  bf16x2 __attribute__((ext_vector_type(2)));
typedef float   f32x4  __attribute__((ext_vector_type(4)));
typedef float   f32x16 __attribute__((ext_vector_type(16)));
typedef unsigned short ushort4v __attribute__((ext_vector_type(4)));
typedef _Float16 half4v __attribute__((ext_vector_type(4)));

#define CIN  128
#define NPT  9
#define KTOT 1152
#define OC   128
#define PX   32
#define NDESC (NPT * PX)
#define KSTEPS 36            // 16x16x32 steps (fallback layout)
#define KSC  12
#define LDBc 392
#define DTOT (9 * 4 * 64 * 64)   // 147456
#define KS32 72              // 32x32x16 K-steps of 16 (mode-3 layout)
#define KSC32 24             // per kh
#define LDR32 392            // Bt row stride bf16: 384 + 8

// prep grid layout
#define PB_WFRAG 72              // 72*256 = 18432 = 4*72*64
#define PB_XPOSE 1024
#define PB_DESC  576
#define PB_ZERO  2048
#define PB_TOTAL (PB_WFRAG + PB_XPOSE + PB_DESC + PB_ZERO)

__device__ __forceinline__ void desc_compute(const float* __restrict__ off, int t,
                                             uint4* __restrict__ desc) {
    int j   = t & 63;
    int i   = (t >> 6) & 63;
    int b   = (t >> 12) & 3;
    int tap = t >> 14;

    float ox = off[(((b * 18) + 2 * tap) << 12) + (i << 6) + j];
    float oy = off[(((b * 18) + 2 * tap + 1) << 12) + (i << 6) + j];
    float px = (float)(i + tap / 3) + ox;
    float py = (float)(j + tap % 3) + oy;
    float fx = floorf(px), fy = floorf(py);
    int qltx = (int)fminf(fmaxf(fx, 0.f), 65.f);
    int qlty = (int)fminf(fmaxf(fy, 0.f), 65.f);
    int qrbx = (int)fminf(fmaxf(fx + 1.f, 0.f), 65.f);
    int qrby = (int)fminf(fmaxf(fy + 1.f, 0.f), 65.f);
    if (px < 1.f || px > 64.f) px = fx;
    if (py < 1.f || py > 64.f) py = fy;
    px = fminf(fmaxf(px, 0.f), 65.f);
    py = fminf(fmaxf(py, 0.f), 65.f);
    float wxl = 1.f + (float)qltx - px;
    float wxr = 1.f - ((float)qrbx - px);
    float wyl = 1.f + (float)qlty - py;
    float wyr = 1.f - ((float)qrby - py);
    float g[4] = { wxl * wyl, wxr * wyr, wxl * wyr, wxr * wyl };
    int qx[4] = { qltx, qrbx, qltx, qrbx };
    int qy[4] = { qlty, qrby, qrby, qlty };
    unsigned short idx[4];
    half4v gh;
    #pragma unroll
    for (int cr = 0; cr < 4; ++cr) {
        bool inb = (qx[cr] >= 1) && (qx[cr] <= 64) && (qy[cr] >= 1) && (qy[cr] <= 64);
        idx[cr] = inb ? (unsigned short)((qx[cr] - 1) * 64 + (qy[cr] - 1)) : 0;
        gh[cr]  = inb ? (_Float16)g[cr] : (_Float16)0.f;
    }
    uint4 rec;
    rec.x = (unsigned)idx[0] | ((unsigned)idx[1] << 16);
    rec.y = (unsigned)idx[2] | ((unsigned)idx[3] << 16);
    __builtin_memcpy(&rec.z, &gh, 8);
    int d = (((b << 6) + i) * 64 + j) * 9 + tap;
    desc[d] = rec;
}

// ---------- fused prep: wfrag32 | xpose | desc | zero(out) ----------
__global__ __launch_bounds__(256) void prep_kernel(
    const float* __restrict__ x, const float* __restrict__ off,
    const float* __restrict__ w, __bf16* __restrict__ wfrag,
    __bf16* __restrict__ xt, uint4* __restrict__ desc,
    float* __restrict__ out)
{
    __shared__ float tile[64][33];
    const int bid = blockIdx.x;
    const int tid = threadIdx.x;

    if (bid < PB_WFRAG) {
        // 32x32x16 A-frag layout: wfrag[((ot4*72+ks)*64+lane)*8+e]
        //   o = ot4*32 + (lane&31), k = ks*16 + (lane>>5)*8 + e
        int t = bid * 256 + tid;          // [0, 18432)
        int lane = t & 63;
        int ks   = (t >> 6) % KS32;
        int ot4  = t / (KS32 * 64);
        int o    = ot4 * 32 + (lane & 31);
        v8bf16 frag;
        #pragma unroll
        for (int e = 0; e < 8; ++e) {
            int k   = ks * 16 + ((lane >> 5) * 8) + e;
            int tap = k >> 7, c = k & 127;
            frag[e] = (__bf16)w[(size_t)o * KTOT + c * NPT + tap];
        }
        *(v8bf16*)(wfrag + (size_t)t * 8) = frag;
    } else if (bid < PB_WFRAG + PB_XPOSE) {
        const int bidx = bid - PB_WFRAG;
        const int b   = bidx >> 8;
        const int hw0 = ((bidx >> 2) & 63) * 64;
        const int c0  = (bidx & 3) * 32;
        #pragma unroll
        for (int r = 0; r < 8; ++r) {
            int c_l  = (tid >> 6) + r * 4;
            int hw_l = tid & 63;
            tile[hw_l][c_l] = x[((size_t)(b * CIN + c0 + c_l) << 12) + hw0 + hw_l];
        }
        __syncthreads();
        #pragma unroll
        for (int r = 0; r < 8; ++r) {
            int hw_l = (tid >> 5) + r * 8;
            int c_l  = tid & 31;
            xt[((size_t)(b * 4096 + hw0 + hw_l)) * CIN + c0 + c_l] = (__bf16)tile[hw_l][c_l];
        }
    } else if (bid < PB_WFRAG + PB_XPOSE + PB_DESC) {
        int t = (bid - PB_WFRAG - PB_XPOSE) * 256 + tid;
        if (t < DTOT) desc_compute(off, t, desc);
    } else {
        int t = (bid - PB_WFRAG - PB_XPOSE - PB_DESC) * 256 + tid;
        f32x4 z = {0.f, 0.f, 0.f, 0.f};
        *(f32x4*)(out + (size_t)t * 4) = z;
    }
}

// ---------- split-K=3, 32x32x16 MFMA, atomic epilogue ----------
__global__ __launch_bounds__(256, 6) void splitk_kernel(
    const uint4* __restrict__ desc, const __bf16* __restrict__ xt,
    const __bf16* __restrict__ wfrag, float* __restrict__ out)
{
    __shared__ __align__(16) __bf16 Bt[PX][LDR32];   // 32 x 392 bf16 = 25088 B

    // XCD swizzle: b rides the low bits
    const int bidx = blockIdx.x;     // [0, 1536)
    const int b    = (bidx & 7) >> 1;
    const int sub  = ((bidx >> 3) << 1) | (bidx & 1);   // [0, 384)
    const int kh3  = sub % 3;
    const int rem  = sub / 3;        // [0, 128)
    const int i    = rem >> 1;
    const int j0   = (rem & 1) * PX;
    const int tid  = threadIdx.x;

    const int tap0 = kh3 * 3;
    const int l  = tid & 63;
    const int wv = tid >> 6;            // 0..3 -> 32-o tile

    const __bf16* xtb = xt + (((size_t)b << 12) * CIN);
    const int pix_base = ((b << 6) + i) * 64 + j0;

    // ---- stage 96 descs (3 taps x 32 px), 24 per wave, quarter-wave gathers ----
    {
        const int q  = l >> 4;
        const int ll = l & 15;

        uint4 qd[6];
        int   pp[6], tt[6];
        #pragma unroll
        for (int m = 0; m < 6; ++m) {
            int dl = wv * 24 + m * 4 + q;    // [0,96)
            tt[m] = dl >> 5;
            pp[m] = dl & 31;
            int d = (pix_base + pp[m]) * 9 + tap0 + tt[m];
            qd[m] = desc[d];
        }

        #pragma unroll
        for (int m = 0; m < 6; ++m) {
            unsigned short idx[4] = {
                (unsigned short)(qd[m].x & 0xffff), (unsigned short)(qd[m].x >> 16),
                (unsigned short)(qd[m].y & 0xffff), (unsigned short)(qd[m].y >> 16) };
            half4v gh;
            unsigned int zz[2] = { qd[m].z, qd[m].w };
            __builtin_memcpy(&gh, &zz, 8);

            float s[8] = {0.f,0.f,0.f,0.f,0.f,0.f,0.f,0.f};
            #pragma unroll
            for (int cr = 0; cr < 4; ++cr) {
                uint4 v = *(const uint4*)(xtb + (size_t)idx[cr] * CIN + 8 * ll);
                float gf = (float)gh[cr];
                unsigned int dw[4] = { v.x, v.y, v.z, v.w };
                #pragma unroll
                for (int e = 0; e < 4; ++e) {
                    float clo, chi;
                    unsigned int lo = dw[e] << 16, hi = dw[e] & 0xffff0000u;
                    __builtin_memcpy(&clo, &lo, 4);
                    __builtin_memcpy(&chi, &hi, 4);
                    s[2 * e]     += gf * clo;
                    s[2 * e + 1] += gf * chi;
                }
            }
            v8bf16 pr;
            #pragma unroll
            for (int e = 0; e < 8; ++e) pr[e] = (__bf16)s[e];
            *(v8bf16*)&Bt[pp[m]][tt[m] * CIN + 8 * ll] = pr;
        }
    }
    __syncthreads();

    // ---- MFMA: wave wv = o-tile [wv*32, wv*32+32) x px [j0, j0+32) ----
    // A: o = lane&31, k = (lane>>5)*8+e ; B: n(px) = lane&31, same k
    f32x16 acc = {0.f,0.f,0.f,0.f,0.f,0.f,0.f,0.f,0.f,0.f,0.f,0.f,0.f,0.f,0.f,0.f};
    const __bf16* brow = &Bt[l & 31][(l >> 5) * 8];
    const __bf16* warow = wfrag + (((size_t)wv * KS32 + kh3 * KSC32) * 64 + l) * 8;

    #pragma unroll 6
    for (int ks = 0; ks < KSC32; ++ks) {
        v8bf16 afrag = *(const v8bf16*)(warow + (size_t)ks * 64 * 8);
        v8bf16 bfrag = *(const v8bf16*)(brow + ks * 16);
        acc = __builtin_amdgcn_mfma_f32_32x32x16_bf16(afrag, bfrag, acc, 0, 0, 0);
    }

    // ---- epilogue: px = l&31, o = wv*32 + 4*(l>>5) + (reg&3) + 8*(reg>>2) ----
    {
        int obase = wv * 32 + 4 * (l >> 5);
        float* opb = out + (((size_t)(b * OC + obase)) << 12) + (i << 6) + j0 + (l & 31);
        #pragma unroll
        for (int reg = 0; reg < 16; ++reg) {
            int oo = (reg & 3) + 8 * (reg >> 2);
            unsafeAtomicAdd(opb + ((size_t)oo << 12), acc[reg]);
        }
    }
}

// ---------- round-5 fused fallback (verified) ----------
__global__ __launch_bounds__(512, 8) void deform_fused_kernel(
    const float* __restrict__ x, const float* __restrict__ off,
    const float* __restrict__ w, const __bf16* __restrict__ wfrag,
    const __bf16* __restrict__ xt, float* __restrict__ out, int mode)
{
    __shared__ __align__(16) __bf16 Bt[PX][LDBc];
    __shared__ __align__(8)  unsigned short sIdxP[NDESC][4];
    __shared__ __align__(8)  _Float16      sGP[NDESC][4];

    const int bidx = blockIdx.x;
    const int b   = bidx >> 8;
    const int i   = (bidx >> 2) & 63;
    const int j0  = ((bidx >> 1) & 1) * PX;
    const int oh  = bidx & 1;
    const int tid = threadIdx.x;

    if (tid < NDESC) {
        int k = tid >> 5, p = tid & 31;
        int j = j0 + p;
        float ox = off[(((b * 18) + 2 * k) * 64 + i) * 64 + j];
        float oy = off[(((b * 18) + 2 * k + 1) * 64 + i) * 64 + j];
        float px = (float)(i + k / 3) + ox;
        float py = (float)(j + k % 3) + oy;
        float fx = floorf(px), fy = floorf(py);
        int qltx = (int)fminf(fmaxf(fx, 0.f), 65.f);
        int qlty = (int)fminf(fmaxf(fy, 0.f), 65.f);
        int qrbx = (int)fminf(fmaxf(fx + 1.f, 0.f), 65.f);
        int qrby = (int)fminf(fmaxf(fy + 1.f, 0.f), 65.f);
        if (px < 1.f || px > 64.f) px = fx;
        if (py < 1.f || py > 64.f) py = fy;
        px = fminf(fmaxf(px, 0.f), 65.f);
        py = fminf(fmaxf(py, 0.f), 65.f);
        float wxl = 1.f + (float)qltx - px;
        float wxr = 1.f - ((float)qrbx - px);
        float wyl = 1.f + (float)qlty - py;
        float wyr = 1.f - ((float)qrby - py);
        float g[4] = { wxl * wyl, wxr * wyr, wxl * wyr, wxr * wyl };
        int qx[4] = { qltx, qrbx, qltx, qrbx };
        int qy[4] = { qlty, qrby, qrby, qlty };
        #pragma unroll
        for (int cr = 0; cr < 4; ++cr) {
            bool inb = (qx[cr] >= 1) && (qx[cr] <= 64) && (qy[cr] >= 1) && (qy[cr] <= 64);
            sIdxP[tid][cr] = inb ? (unsigned short)((qx[cr] - 1) * 64 + (qy[cr] - 1)) : 0;
            sGP[tid][cr]   = inb ? (_Float16)g[cr] : (_Float16)0.f;
        }
    }
    __syncthreads();

    const int l    = tid & 63;
    const int wv   = tid >> 6;
    const int ot   = oh * 4 + (wv & 3);
    const int ph   = wv >> 2;
    const int quad = l >> 4;
    const int lr   = l & 15;

    f32x4 acc = {0.f, 0.f, 0.f, 0.f};
    const __bf16* xtb = xt + ((size_t)b * 4096) * CIN;
    const float*  xb  = x + ((size_t)b * CIN << 12);
    const __bf16* brow = &Bt[ph * 16 + lr][quad * 8];

    for (int t = 0; t < 3; ++t) {
        if (mode == 2) {
            #pragma unroll 4
            for (int dd = 0; dd < KSC; ++dd) {
                int dl = wv * KSC + dd;
                int tap_l = dl >> 5, p = dl & 31;
                int d = t * 96 + dl;
                ushort4v id = *(const ushort4v*)&sIdxP[d][0];
                half4v   gh = *(const half4v*)&sGP[d][0];
                float s0 = 0.f, s1 = 0.f;
                #pragma unroll
                for (int cr = 0; cr < 4; ++cr) {
                    unsigned int v = *(const unsigned int*)(xtb + (size_t)id[cr] * CIN + 2 * l);
                    float c0v, c1v;
                    unsigned int lo = v << 16, hi = v & 0xffff0000u;
                    __builtin_memcpy(&c0v, &lo, 4);
                    __builtin_memcpy(&c1v, &hi, 4);
                    float gf = (float)gh[cr];
                    s0 += gf * c0v;
                    s1 += gf * c1v;
                }
                bf16x2 pr = { (__bf16)s0, (__bf16)s1 };
                *(bf16x2*)&Bt[p][tap_l * CIN + 2 * l] = pr;
            }
        } else {
            for (int dd = 0; dd < KSC; ++dd) {
                int dl = wv * KSC + dd;
                int tap_l = dl >> 5, p = dl & 31;
                int d = t * 96 + dl;
                ushort4v id = *(const ushort4v*)&sIdxP[d][0];
                half4v   gh = *(const half4v*)&sGP[d][0];
                float s0 = 0.f, s1 = 0.f;
                #pragma unroll
                for (int cr = 0; cr < 4; ++cr) {
                    float gf = (float)gh[cr];
                    s0 += gf * xb[((size_t)(2 * l) << 12) + id[cr]];
                    s1 += gf * xb[((size_t)(2 * l + 1) << 12) + id[cr]];
                }
                bf16x2 pr = { (__bf16)s0, (__bf16)s1 };
                *(bf16x2*)&Bt[p][tap_l * CIN + 2 * l] = pr;
            }
        }
        __syncthreads();

        #pragma unroll 4
        for (int ks = 0; ks < KSC; ++ks) {
            int ks_g = t * KSC + ks;
            v8bf16 bfrag = *(const v8bf16*)(brow + ks * 32);
            v8bf16 afrag;
            if (mode >= 1) {
                afrag = *(const v8bf16*)(wfrag + (((size_t)ot * KSTEPS + ks_g) * 64 + l) * 8);
            } else {
                int o = ot * 16 + lr;
                #pragma unroll
                for (int e = 0; e < 8; ++e) {
                    int k = ks_g * 32 + quad * 8 + e;
                    int tap = k >> 7, c = k & 127;
                    afrag[e] = (__bf16)w[(size_t)o * KTOT + c * NPT + tap];
                }
            }
            acc = __builtin_amdgcn_mfma_f32_16x16x32_bf16(afrag, bfrag, acc, 0, 0, 0);
        }
        if (t < 2) __syncthreads();
    }

    {
        int obase = ot * 16 + quad * 4;
        float* op = out + (((size_t)(b * OC + obase)) << 12) + (i << 6) + j0 + ph * 16 + lr;
        #pragma unroll
        for (int r = 0; r < 4; ++r)
            op[(size_t)r << 12] = acc[r];
    }
}

// standalone prep pieces for fallback modes (old 16x16x32 wfrag layout)
__global__ __launch_bounds__(256) void wfrag_kernel(const float* __restrict__ w,
                                                    __bf16* __restrict__ wfrag) {
    int t = blockIdx.x * 256 + threadIdx.x;
    if (t >= 8 * KSTEPS * 64) return;
    int lane = t & 63;
    int ks   = (t >> 6) % KSTEPS;
    int ot   = t / (KSTEPS * 64);
    int o    = ot * 16 + (lane & 15);
    v8bf16 frag;
    #pragma unroll
    for (int e = 0; e < 8; ++e) {
        int k   = ks * 32 + (lane >> 4) * 8 + e;
        int tap = k >> 7, c = k & 127;
        frag[e] = (__bf16)w[(size_t)o * KTOT + c * NPT + tap];
    }
    *(v8bf16*)(wfrag + (size_t)t * 8) = frag;
}

__global__ __launch_bounds__(256) void xpose_kernel(const float* __restrict__ x,
                                                    __bf16* __restrict__ xt) {
    __shared__ float tile[64][33];
    const int bidx = blockIdx.x;
    const int b   = bidx >> 8;
    const int hw0 = ((bidx >> 2) & 63) * 64;
    const int c0  = (bidx & 3) * 32;
    const int tid = threadIdx.x;
    #pragma unroll
    for (int r = 0; r < 8; ++r) {
        int c_l  = (tid >> 6) + r * 4;
        int hw_l = tid & 63;
        tile[hw_l][c_l] = x[((size_t)(b * CIN + c0 + c_l) << 12) + hw0 + hw_l];
    }
    __syncthreads();
    #pragma unroll
    for (int r = 0; r < 8; ++r) {
        int hw_l = (tid >> 5) + r * 8;
        int c_l  = tid & 31;
        xt[((size_t)(b * 4096 + hw0 + hw_l)) * CIN + c0 + c_l] = (__bf16)tile[hw_l][c_l];
    }
}

extern "C" void kernel_launch(void* const* d_in, const int* in_sizes, int n_in,
                              void* d_out, int out_size, void* d_ws, size_t ws_size,
                              hipStream_t stream) {
    const float* x   = (const float*)d_in[0];
    const float* off = (const float*)d_in[1];
    const float* w   = (const float*)d_in[2];
    float* out = (float*)d_out;

    const size_t wfrag_bytes = (size_t)OC * KTOT * sizeof(__bf16);        // 294912
    const size_t xt_bytes    = (size_t)4 * 4096 * CIN * sizeof(__bf16);   // 4 MB
    const size_t desc_bytes  = (size_t)DTOT * 16;                         // 2.36 MB

    int mode = 0;
    if (ws_size >= wfrag_bytes + xt_bytes + desc_bytes) mode = 3;
    else if (ws_size >= wfrag_bytes + xt_bytes) mode = 2;
    else if (ws_size >= wfrag_bytes) mode = 1;

    __bf16* wfrag = (__bf16*)d_ws;
    __bf16* xt    = (__bf16*)((char*)d_ws + wfrag_bytes);
    uint4*  desc  = (uint4*) ((char*)d_ws + wfrag_bytes + xt_bytes);

    if (mode == 3) {
        prep_kernel<<<PB_TOTAL, 256, 0, stream>>>(x, off, w, wfrag, xt, desc, out);
        splitk_kernel<<<1536, 256, 0, stream>>>(desc, xt, wfrag, out);
    } else {
        if (mode >= 1)
            wfrag_kernel<<<(8 * KSTEPS * 64 + 255) / 256, 256, 0, stream>>>(w, wfrag);
        if (mode >= 2)
            xpose_kernel<<<4 * 64 * 4, 256, 0, stream>>>(x, xt);
        deform_fused_kernel<<<4 * 64 * 2 * 2, 512, 0, stream>>>(x, off, w, wfrag, xt, out, mode);
    }
}

// Round 12
// 95.311 us; speedup vs baseline: 1.0170x; 1.0170x over previous
//
#include <hip/hip_runtime.h>

// DeformConv2D b=4,c=128,H=W=64,outc=128,KS=3,PAD=1,N=9
// 2-launch pipeline (mode 3):
//   prep   : wfrag32 + xpose + desc + zero(out), fused, branch on blockIdx
//   splitk : grid 1536 = b4*i64*jh2*kh3 (XCD-swizzled), block = 32px x 128o,
//            256 thr (4 waves; wave = 32o x 32px via mfma_f32_32x32x16_bf16).
//            Staging: register-batched gathers (12 in flight per half) for MLP.
//            Epilogue: atomicAdd into zeroed out.
// Fallback (mode<=2): round-5 fused kernel (verified, 16x16x32 path).

typedef __bf16  v8bf16 __attribute__((ext_vector_type(8)));
typedef __bf16  bf16x2 __attribute__((ext_vector_type(2)));
typedef float   f32x4  __attribute__((ext_vector_type(4)));
typedef float   f32x16 __attribute__((ext_vector_type(16)));
typedef unsigned short ushort4v __attribute__((ext_vector_type(4)));
typedef _Float16 half4v __attribute__((ext_vector_type(4)));

#define CIN  128
#define NPT  9
#define KTOT 1152
#define OC   128
#define PX   32
#define NDESC (NPT * PX)
#define KSTEPS 36            // 16x16x32 steps (fallback layout)
#define KSC  12
#define LDBc 392
#define DTOT (9 * 4 * 64 * 64)   // 147456
#define KS32 72              // 32x32x16 K-steps of 16 (mode-3 layout)
#define KSC32 24             // per kh
#define LDR32 392            // Bt row stride bf16: 384 + 8

// prep grid layout
#define PB_WFRAG 72              // 72*256 = 18432 = 4*72*64
#define PB_XPOSE 1024
#define PB_DESC  576
#define PB_ZERO  2048
#define PB_TOTAL (PB_WFRAG + PB_XPOSE + PB_DESC + PB_ZERO)

__device__ __forceinline__ void desc_compute(const float* __restrict__ off, int t,
                                             uint4* __restrict__ desc) {
    int j   = t & 63;
    int i   = (t >> 6) & 63;
    int b   = (t >> 12) & 3;
    int tap = t >> 14;

    float ox = off[(((b * 18) + 2 * tap) << 12) + (i << 6) + j];
    float oy = off[(((b * 18) + 2 * tap + 1) << 12) + (i << 6) + j];
    float px = (float)(i + tap / 3) + ox;
    float py = (float)(j + tap % 3) + oy;
    float fx = floorf(px), fy = floorf(py);
    int qltx = (int)fminf(fmaxf(fx, 0.f), 65.f);
    int qlty = (int)fminf(fmaxf(fy, 0.f), 65.f);
    int qrbx = (int)fminf(fmaxf(fx + 1.f, 0.f), 65.f);
    int qrby = (int)fminf(fmaxf(fy + 1.f, 0.f), 65.f);
    if (px < 1.f || px > 64.f) px = fx;
    if (py < 1.f || py > 64.f) py = fy;
    px = fminf(fmaxf(px, 0.f), 65.f);
    py = fminf(fmaxf(py, 0.f), 65.f);
    float wxl = 1.f + (float)qltx - px;
    float wxr = 1.f - ((float)qrbx - px);
    float wyl = 1.f + (float)qlty - py;
    float wyr = 1.f - ((float)qrby - py);
    float g[4] = { wxl * wyl, wxr * wyr, wxl * wyr, wxr * wyl };
    int qx[4] = { qltx, qrbx, qltx, qrbx };
    int qy[4] = { qlty, qrby, qrby, qlty };
    unsigned short idx[4];
    half4v gh;
    #pragma unroll
    for (int cr = 0; cr < 4; ++cr) {
        bool inb = (qx[cr] >= 1) && (qx[cr] <= 64) && (qy[cr] >= 1) && (qy[cr] <= 64);
        idx[cr] = inb ? (unsigned short)((qx[cr] - 1) * 64 + (qy[cr] - 1)) : 0;
        gh[cr]  = inb ? (_Float16)g[cr] : (_Float16)0.f;
    }
    uint4 rec;
    rec.x = (unsigned)idx[0] | ((unsigned)idx[1] << 16);
    rec.y = (unsigned)idx[2] | ((unsigned)idx[3] << 16);
    __builtin_memcpy(&rec.z, &gh, 8);
    int d = (((b << 6) + i) * 64 + j) * 9 + tap;
    desc[d] = rec;
}

// ---------- fused prep: wfrag32 | xpose | desc | zero(out) ----------
__global__ __launch_bounds__(256) void prep_kernel(
    const float* __restrict__ x, const float* __restrict__ off,
    const float* __restrict__ w, __bf16* __restrict__ wfrag,
    __bf16* __restrict__ xt, uint4* __restrict__ desc,
    float* __restrict__ out)
{
    __shared__ float tile[64][33];
    const int bid = blockIdx.x;
    const int tid = threadIdx.x;

    if (bid < PB_WFRAG) {
        // 32x32x16 A-frag layout: wfrag[((ot4*72+ks)*64+lane)*8+e]
        //   o = ot4*32 + (lane&31), k = ks*16 + (lane>>5)*8 + e
        int t = bid * 256 + tid;          // [0, 18432)
        int lane = t & 63;
        int ks   = (t >> 6) % KS32;
        int ot4  = t / (KS32 * 64);
        int o    = ot4 * 32 + (lane & 31);
        v8bf16 frag;
        #pragma unroll
        for (int e = 0; e < 8; ++e) {
            int k   = ks * 16 + ((lane >> 5) * 8) + e;
            int tap = k >> 7, c = k & 127;
            frag[e] = (__bf16)w[(size_t)o * KTOT + c * NPT + tap];
        }
        *(v8bf16*)(wfrag + (size_t)t * 8) = frag;
    } else if (bid < PB_WFRAG + PB_XPOSE) {
        const int bidx = bid - PB_WFRAG;
        const int b   = bidx >> 8;
        const int hw0 = ((bidx >> 2) & 63) * 64;
        const int c0  = (bidx & 3) * 32;
        #pragma unroll
        for (int r = 0; r < 8; ++r) {
            int c_l  = (tid >> 6) + r * 4;
            int hw_l = tid & 63;
            tile[hw_l][c_l] = x[((size_t)(b * CIN + c0 + c_l) << 12) + hw0 + hw_l];
        }
        __syncthreads();
        #pragma unroll
        for (int r = 0; r < 8; ++r) {
            int hw_l = (tid >> 5) + r * 8;
            int c_l  = tid & 31;
            xt[((size_t)(b * 4096 + hw0 + hw_l)) * CIN + c0 + c_l] = (__bf16)tile[hw_l][c_l];
        }
    } else if (bid < PB_WFRAG + PB_XPOSE + PB_DESC) {
        int t = (bid - PB_WFRAG - PB_XPOSE) * 256 + tid;
        if (t < DTOT) desc_compute(off, t, desc);
    } else {
        int t = (bid - PB_WFRAG - PB_XPOSE - PB_DESC) * 256 + tid;
        f32x4 z = {0.f, 0.f, 0.f, 0.f};
        *(f32x4*)(out + (size_t)t * 4) = z;
    }
}

// ---------- split-K=3, 32x32x16 MFMA, register-batched staging ----------
__global__ __launch_bounds__(256) void splitk_kernel(
    const uint4* __restrict__ desc, const __bf16* __restrict__ xt,
    const __bf16* __restrict__ wfrag, float* __restrict__ out)
{
    __shared__ __align__(16) __bf16 Bt[PX][LDR32];   // 32 x 392 bf16 = 25088 B

    // XCD swizzle: b rides the low bits
    const int bidx = blockIdx.x;     // [0, 1536)
    const int b    = (bidx & 7) >> 1;
    const int sub  = ((bidx >> 3) << 1) | (bidx & 1);   // [0, 384)
    const int kh3  = sub % 3;
    const int rem  = sub / 3;        // [0, 128)
    const int i    = rem >> 1;
    const int j0   = (rem & 1) * PX;
    const int tid  = threadIdx.x;

    const int tap0 = kh3 * 3;
    const int l  = tid & 63;
    const int wv = tid >> 6;            // 0..3 -> 32-o tile

    const __bf16* xtb = xt + (((size_t)b << 12) * CIN);
    const int pix_base = ((b << 6) + i) * 64 + j0;

    // ---- stage 96 descs (3 taps x 32 px), 24 per wave ----
    // quarter-wave gathers, register-batched: 12 loads in flight per half
    {
        const int q  = l >> 4;
        const int ll = l & 15;
        const __bf16* base = xtb + 8 * ll;

        uint4 qd[6];
        int   pp[6], tt[6];
        #pragma unroll
        for (int m = 0; m < 6; ++m) {
            int dl = wv * 24 + m * 4 + q;    // [0,96)
            tt[m] = dl >> 5;
            pp[m] = dl & 31;
            int d = (pix_base + pp[m]) * 9 + tap0 + tt[m];
            qd[m] = desc[d];
        }

        #pragma unroll
        for (int h = 0; h < 2; ++h) {
            uint4  v[3][4];
            half4v gh[3];
            // issue all 12 gathers of this half before any FMA
            #pragma unroll
            for (int m = 0; m < 3; ++m) {
                uint4 qm = qd[h * 3 + m];
                unsigned int zz[2] = { qm.z, qm.w };
                __builtin_memcpy(&gh[m], &zz, 8);
                unsigned short idx[4] = {
                    (unsigned short)(qm.x & 0xffff), (unsigned short)(qm.x >> 16),
                    (unsigned short)(qm.y & 0xffff), (unsigned short)(qm.y >> 16) };
                #pragma unroll
                for (int cr = 0; cr < 4; ++cr)
                    v[m][cr] = *(const uint4*)(base + (size_t)idx[cr] * CIN);
            }
            // consume
            #pragma unroll
            for (int m = 0; m < 3; ++m) {
                float s[8] = {0.f,0.f,0.f,0.f,0.f,0.f,0.f,0.f};
                #pragma unroll
                for (int cr = 0; cr < 4; ++cr) {
                    float gf = (float)gh[m][cr];
                    unsigned int dw[4] = { v[m][cr].x, v[m][cr].y, v[m][cr].z, v[m][cr].w };
                    #pragma unroll
                    for (int e = 0; e < 4; ++e) {
                        float clo, chi;
                        unsigned int lo = dw[e] << 16, hi = dw[e] & 0xffff0000u;
                        __builtin_memcpy(&clo, &lo, 4);
                        __builtin_memcpy(&chi, &hi, 4);
                        s[2 * e]     += gf * clo;
                        s[2 * e + 1] += gf * chi;
                    }
                }
                v8bf16 pr;
                #pragma unroll
                for (int e = 0; e < 8; ++e) pr[e] = (__bf16)s[e];
                int mm = h * 3 + m;
                *(v8bf16*)&Bt[pp[mm]][tt[mm] * CIN + 8 * ll] = pr;
            }
        }
    }
    __syncthreads();

    // ---- MFMA: wave wv = o-tile [wv*32, wv*32+32) x px [j0, j0+32) ----
    f32x16 acc = {0.f,0.f,0.f,0.f,0.f,0.f,0.f,0.f,0.f,0.f,0.f,0.f,0.f,0.f,0.f,0.f};
    const __bf16* brow = &Bt[l & 31][(l >> 5) * 8];
    const __bf16* warow = wfrag + (((size_t)wv * KS32 + kh3 * KSC32) * 64 + l) * 8;

    #pragma unroll 6
    for (int ks = 0; ks < KSC32; ++ks) {
        v8bf16 afrag = *(const v8bf16*)(warow + (size_t)ks * 64 * 8);
        v8bf16 bfrag = *(const v8bf16*)(brow + ks * 16);
        acc = __builtin_amdgcn_mfma_f32_32x32x16_bf16(afrag, bfrag, acc, 0, 0, 0);
    }

    // ---- epilogue: px = l&31, o = wv*32 + 4*(l>>5) + (reg&3) + 8*(reg>>2) ----
    {
        int obase = wv * 32 + 4 * (l >> 5);
        float* opb = out + (((size_t)(b * OC + obase)) << 12) + (i << 6) + j0 + (l & 31);
        #pragma unroll
        for (int reg = 0; reg < 16; ++reg) {
            int oo = (reg & 3) + 8 * (reg >> 2);
            unsafeAtomicAdd(opb + ((size_t)oo << 12), acc[reg]);
        }
    }
}

// ---------- round-5 fused fallback (verified) ----------
__global__ __launch_bounds__(512, 8) void deform_fused_kernel(
    const float* __restrict__ x, const float* __restrict__ off,
    const float* __restrict__ w, const __bf16* __restrict__ wfrag,
    const __bf16* __restrict__ xt, float* __restrict__ out, int mode)
{
    __shared__ __align__(16) __bf16 Bt[PX][LDBc];
    __shared__ __align__(8)  unsigned short sIdxP[NDESC][4];
    __shared__ __align__(8)  _Float16      sGP[NDESC][4];

    const int bidx = blockIdx.x;
    const int b   = bidx >> 8;
    const int i   = (bidx >> 2) & 63;
    const int j0  = ((bidx >> 1) & 1) * PX;
    const int oh  = bidx & 1;
    const int tid = threadIdx.x;

    if (tid < NDESC) {
        int k = tid >> 5, p = tid & 31;
        int j = j0 + p;
        float ox = off[(((b * 18) + 2 * k) * 64 + i) * 64 + j];
        float oy = off[(((b * 18) + 2 * k + 1) * 64 + i) * 64 + j];
        float px = (float)(i + k / 3) + ox;
        float py = (float)(j + k % 3) + oy;
        float fx = floorf(px), fy = floorf(py);
        int qltx = (int)fminf(fmaxf(fx, 0.f), 65.f);
        int qlty = (int)fminf(fmaxf(fy, 0.f), 65.f);
        int qrbx = (int)fminf(fmaxf(fx + 1.f, 0.f), 65.f);
        int qrby = (int)fminf(fmaxf(fy + 1.f, 0.f), 65.f);
        if (px < 1.f || px > 64.f) px = fx;
        if (py < 1.f || py > 64.f) py = fy;
        px = fminf(fmaxf(px, 0.f), 65.f);
        py = fminf(fmaxf(py, 0.f), 65.f);
        float wxl = 1.f + (float)qltx - px;
        float wxr = 1.f - ((float)qrbx - px);
        float wyl = 1.f + (float)qlty - py;
        float wyr = 1.f - ((float)qrby - py);
        float g[4] = { wxl * wyl, wxr * wyr, wxl * wyr, wxr * wyl };
        int qx[4] = { qltx, qrbx, qltx, qrbx };
        int qy[4] = { qlty, qrby, qrby, qlty };
        #pragma unroll
        for (int cr = 0; cr < 4; ++cr) {
            bool inb = (qx[cr] >= 1) && (qx[cr] <= 64) && (qy[cr] >= 1) && (qy[cr] <= 64);
            sIdxP[tid][cr] = inb ? (unsigned short)((qx[cr] - 1) * 64 + (qy[cr] - 1)) : 0;
            sGP[tid][cr]   = inb ? (_Float16)g[cr] : (_Float16)0.f;
        }
    }
    __syncthreads();

    const int l    = tid & 63;
    const int wv   = tid >> 6;
    const int ot   = oh * 4 + (wv & 3);
    const int ph   = wv >> 2;
    const int quad = l >> 4;
    const int lr   = l & 15;

    f32x4 acc = {0.f, 0.f, 0.f, 0.f};
    const __bf16* xtb = xt + ((size_t)b * 4096) * CIN;
    const float*  xb  = x + ((size_t)b * CIN << 12);
    const __bf16* brow = &Bt[ph * 16 + lr][quad * 8];

    for (int t = 0; t < 3; ++t) {
        if (mode == 2) {
            #pragma unroll 4
            for (int dd = 0; dd < KSC; ++dd) {
                int dl = wv * KSC + dd;
                int tap_l = dl >> 5, p = dl & 31;
                int d = t * 96 + dl;
                ushort4v id = *(const ushort4v*)&sIdxP[d][0];
                half4v   gh = *(const half4v*)&sGP[d][0];
                float s0 = 0.f, s1 = 0.f;
                #pragma unroll
                for (int cr = 0; cr < 4; ++cr) {
                    unsigned int v = *(const unsigned int*)(xtb + (size_t)id[cr] * CIN + 2 * l);
                    float c0v, c1v;
                    unsigned int lo = v << 16, hi = v & 0xffff0000u;
                    __builtin_memcpy(&c0v, &lo, 4);
                    __builtin_memcpy(&c1v, &hi, 4);
                    float gf = (float)gh[cr];
                    s0 += gf * c0v;
                    s1 += gf * c1v;
                }
                bf16x2 pr = { (__bf16)s0, (__bf16)s1 };
                *(bf16x2*)&Bt[p][tap_l * CIN + 2 * l] = pr;
            }
        } else {
            for (int dd = 0; dd < KSC; ++dd) {
                int dl = wv * KSC + dd;
                int tap_l = dl >> 5, p = dl & 31;
                int d = t * 96 + dl;
                ushort4v id = *(const ushort4v*)&sIdxP[d][0];
                half4v   gh = *(const half4v*)&sGP[d][0];
                float s0 = 0.f, s1 = 0.f;
                #pragma unroll
                for (int cr = 0; cr < 4; ++cr) {
                    float gf = (float)gh[cr];
                    s0 += gf * xb[((size_t)(2 * l) << 12) + id[cr]];
                    s1 += gf * xb[((size_t)(2 * l + 1) << 12) + id[cr]];
                }
                bf16x2 pr = { (__bf16)s0, (__bf16)s1 };
                *(bf16x2*)&Bt[p][tap_l * CIN + 2 * l] = pr;
            }
        }
        __syncthreads();

        #pragma unroll 4
        for (int ks = 0; ks < KSC; ++ks) {
            int ks_g = t * KSC + ks;
            v8bf16 bfrag = *(const v8bf16*)(brow + ks * 32);
            v8bf16 afrag;
            if (mode >= 1) {
                afrag = *(const v8bf16*)(wfrag + (((size_t)ot * KSTEPS + ks_g) * 64 + l) * 8);
            } else {
                int o = ot * 16 + lr;
                #pragma unroll
                for (int e = 0; e < 8; ++e) {
                    int k = ks_g * 32 + quad * 8 + e;
                    int tap = k >> 7, c = k & 127;
                    afrag[e] = (__bf16)w[(size_t)o * KTOT + c * NPT + tap];
                }
            }
            acc = __builtin_amdgcn_mfma_f32_16x16x32_bf16(afrag, bfrag, acc, 0, 0, 0);
        }
        if (t < 2) __syncthreads();
    }

    {
        int obase = ot * 16 + quad * 4;
        float* op = out + (((size_t)(b * OC + obase)) << 12) + (i << 6) + j0 + ph * 16 + lr;
        #pragma unroll
        for (int r = 0; r < 4; ++r)
            op[(size_t)r << 12] = acc[r];
    }
}

// standalone prep pieces for fallback modes (old 16x16x32 wfrag layout)
__global__ __launch_bounds__(256) void wfrag_kernel(const float* __restrict__ w,
                                                    __bf16* __restrict__ wfrag) {
    int t = blockIdx.x * 256 + threadIdx.x;
    if (t >= 8 * KSTEPS * 64) return;
    int lane = t & 63;
    int ks   = (t >> 6) % KSTEPS;
    int ot   = t / (KSTEPS * 64);
    int o    = ot * 16 + (lane & 15);
    v8bf16 frag;
    #pragma unroll
    for (int e = 0; e < 8; ++e) {
        int k   = ks * 32 + (lane >> 4) * 8 + e;
        int tap = k >> 7, c = k & 127;
        frag[e] = (__bf16)w[(size_t)o * KTOT + c * NPT + tap];
    }
    *(v8bf16*)(wfrag + (size_t)t * 8) = frag;
}

__global__ __launch_bounds__(256) void xpose_kernel(const float* __restrict__ x,
                                                    __bf16* __restrict__ xt) {
    __shared__ float tile[64][33];
    const int bidx = blockIdx.x;
    const int b   = bidx >> 8;
    const int hw0 = ((bidx >> 2) & 63) * 64;
    const int c0  = (bidx & 3) * 32;
    const int tid = threadIdx.x;
    #pragma unroll
    for (int r = 0; r < 8; ++r) {
        int c_l  = (tid >> 6) + r * 4;
        int hw_l = tid & 63;
        tile[hw_l][c_l] = x[((size_t)(b * CIN + c0 + c_l) << 12) + hw0 + hw_l];
    }
    __syncthreads();
    #pragma unroll
    for (int r = 0; r < 8; ++r) {
        int hw_l = (tid >> 5) + r * 8;
        int c_l  = tid & 31;
        xt[((size_t)(b * 4096 + hw0 + hw_l)) * CIN + c0 + c_l] = (__bf16)tile[hw_l][c_l];
    }
}

extern "C" void kernel_launch(void* const* d_in, const int* in_sizes, int n_in,
                              void* d_out, int out_size, void* d_ws, size_t ws_size,
                              hipStream_t stream) {
    const float* x   = (const float*)d_in[0];
    const float* off = (const float*)d_in[1];
    const float* w   = (const float*)d_in[2];
    float* out = (float*)d_out;

    const size_t wfrag_bytes = (size_t)OC * KTOT * sizeof(__bf16);        // 294912
    const size_t xt_bytes    = (size_t)4 * 4096 * CIN * sizeof(__bf16);   // 4 MB
    const size_t desc_bytes  = (size_t)DTOT * 16;                         // 2.36 MB

    int mode = 0;
    if (ws_size >= wfrag_bytes + xt_bytes + desc_bytes) mode = 3;
    else if (ws_size >= wfrag_bytes + xt_bytes) mode = 2;
    else if (ws_size >= wfrag_bytes) mode = 1;

    __bf16* wfrag = (__bf16*)d_ws;
    __bf16* xt    = (__bf16*)((char*)d_ws + wfrag_bytes);
    uint4*  desc  = (uint4*) ((char*)d_ws + wfrag_bytes + xt_bytes);

    if (mode == 3) {
        prep_kernel<<<PB_TOTAL, 256, 0, stream>>>(x, off, w, wfrag, xt, desc, out);
        splitk_kernel<<<1536, 256, 0, stream>>>(desc, xt, wfrag, out);
    } else {
        if (mode >= 1)
            wfrag_kernel<<<(8 * KSTEPS * 64 + 255) / 256, 256, 0, stream>>>(w, wfrag);
        if (mode >= 2)
            xpose_kernel<<<4 * 64 * 4, 256, 0, stream>>>(x, xt);
        deform_fused_kernel<<<4 * 64 * 2 * 2, 512, 0, stream>>>(x, off, w, wfrag, xt, out, mode);
    }
}

// Round 13
// 92.506 us; speedup vs baseline: 1.0479x; 1.0303x over previous
//
#include <hip/hip_runtime.h>

// DeformConv2D b=4,c=128,H=W=64,outc=128,KS=3,PAD=1,N=9
// 2-launch pipeline (mode 3):
//   prep   : wfrag32 + xpose + zero(out), fused, branch on blockIdx
//   splitk : grid 1536 = b4*i64*jh2*kh3 (XCD-swizzled), block = 32px x 128o,
//            256 thr (4 waves; wave = 32o x 32px via mfma_f32_32x32x16_bf16).
//            Phase0: 96 descs computed inline -> LDS (no global round-trip).
//            Staging: register-batched quarter-wave dwordx4 gathers.
//            Epilogue: atomicAdd into zeroed out.
// Fallback (mode<=2): round-5 fused kernel (verified, 16x16x32 path).

typedef __bf16  v8bf16 __attribute__((ext_vector_type(8)));
typedef __bf16  bf16x2 __attribute__((ext_vector_type(2)));
typedef float   f32x4  __attribute__((ext_vector_type(4)));
typedef float   f32x16 __attribute__((ext_vector_type(16)));
typedef unsigned short ushort4v __attribute__((ext_vector_type(4)));
typedef _Float16 half4v __attribute__((ext_vector_type(4)));

#define CIN  128
#define NPT  9
#define KTOT 1152
#define OC   128
#define PX   32
#define NDESC (NPT * PX)
#define KSTEPS 36            // 16x16x32 steps (fallback layout)
#define KSC  12
#define LDBc 392
#define KS32 72              // 32x32x16 K-steps of 16 (mode-3 layout)
#define KSC32 24             // per kh
#define LDR32 392            // Bt row stride bf16: 384 + 8

// prep grid layout
#define PB_WFRAG 72              // 72*256 = 18432 = 4*72*64
#define PB_XPOSE 1024
#define PB_ZERO  2048
#define PB_TOTAL (PB_WFRAG + PB_XPOSE + PB_ZERO)

// geometry -> packed descriptor {idx4 u16, g4 f16}
__device__ __forceinline__ uint4 desc_make(const float* __restrict__ off,
                                           int b, int i, int j, int tap) {
    float ox = off[(((b * 18) + 2 * tap) << 12) + (i << 6) + j];
    float oy = off[(((b * 18) + 2 * tap + 1) << 12) + (i << 6) + j];
    float px = (float)(i + tap / 3) + ox;
    float py = (float)(j + tap % 3) + oy;
    float fx = floorf(px), fy = floorf(py);
    int qltx = (int)fminf(fmaxf(fx, 0.f), 65.f);
    int qlty = (int)fminf(fmaxf(fy, 0.f), 65.f);
    int qrbx = (int)fminf(fmaxf(fx + 1.f, 0.f), 65.f);
    int qrby = (int)fminf(fmaxf(fy + 1.f, 0.f), 65.f);
    if (px < 1.f || px > 64.f) px = fx;
    if (py < 1.f || py > 64.f) py = fy;
    px = fminf(fmaxf(px, 0.f), 65.f);
    py = fminf(fmaxf(py, 0.f), 65.f);
    float wxl = 1.f + (float)qltx - px;
    float wxr = 1.f - ((float)qrbx - px);
    float wyl = 1.f + (float)qlty - py;
    float wyr = 1.f - ((float)qrby - py);
    float g[4] = { wxl * wyl, wxr * wyr, wxl * wyr, wxr * wyl };
    int qx[4] = { qltx, qrbx, qltx, qrbx };
    int qy[4] = { qlty, qrby, qrby, qlty };
    unsigned short idx[4];
    half4v gh;
    #pragma unroll
    for (int cr = 0; cr < 4; ++cr) {
        bool inb = (qx[cr] >= 1) && (qx[cr] <= 64) && (qy[cr] >= 1) && (qy[cr] <= 64);
        idx[cr] = inb ? (unsigned short)((qx[cr] - 1) * 64 + (qy[cr] - 1)) : 0;
        gh[cr]  = inb ? (_Float16)g[cr] : (_Float16)0.f;
    }
    uint4 rec;
    rec.x = (unsigned)idx[0] | ((unsigned)idx[1] << 16);
    rec.y = (unsigned)idx[2] | ((unsigned)idx[3] << 16);
    __builtin_memcpy(&rec.z, &gh, 8);
    return rec;
}

// ---------- fused prep: wfrag32 | xpose | zero(out) ----------
__global__ __launch_bounds__(256) void prep_kernel(
    const float* __restrict__ x, const float* __restrict__ w,
    __bf16* __restrict__ wfrag, __bf16* __restrict__ xt,
    float* __restrict__ out)
{
    __shared__ float tile[64][33];
    const int bid = blockIdx.x;
    const int tid = threadIdx.x;

    if (bid < PB_WFRAG) {
        // 32x32x16 A-frag layout: wfrag[((ot4*72+ks)*64+lane)*8+e]
        //   o = ot4*32 + (lane&31), k = ks*16 + (lane>>5)*8 + e
        int t = bid * 256 + tid;          // [0, 18432)
        int lane = t & 63;
        int ks   = (t >> 6) % KS32;
        int ot4  = t / (KS32 * 64);
        int o    = ot4 * 32 + (lane & 31);
        v8bf16 frag;
        #pragma unroll
        for (int e = 0; e < 8; ++e) {
            int k   = ks * 16 + ((lane >> 5) * 8) + e;
            int tap = k >> 7, c = k & 127;
            frag[e] = (__bf16)w[(size_t)o * KTOT + c * NPT + tap];
        }
        *(v8bf16*)(wfrag + (size_t)t * 8) = frag;
    } else if (bid < PB_WFRAG + PB_XPOSE) {
        const int bidx = bid - PB_WFRAG;
        const int b   = bidx >> 8;
        const int hw0 = ((bidx >> 2) & 63) * 64;
        const int c0  = (bidx & 3) * 32;
        #pragma unroll
        for (int r = 0; r < 8; ++r) {
            int c_l  = (tid >> 6) + r * 4;
            int hw_l = tid & 63;
            tile[hw_l][c_l] = x[((size_t)(b * CIN + c0 + c_l) << 12) + hw0 + hw_l];
        }
        __syncthreads();
        #pragma unroll
        for (int r = 0; r < 8; ++r) {
            int hw_l = (tid >> 5) + r * 8;
            int c_l  = tid & 31;
            xt[((size_t)(b * 4096 + hw0 + hw_l)) * CIN + c0 + c_l] = (__bf16)tile[hw_l][c_l];
        }
    } else {
        int t = (bid - PB_WFRAG - PB_XPOSE) * 256 + tid;
        f32x4 z = {0.f, 0.f, 0.f, 0.f};
        *(f32x4*)(out + (size_t)t * 4) = z;
    }
}

// ---------- split-K=3, inline desc, 32x32x16 MFMA, atomic epilogue ----------
__global__ __launch_bounds__(256) void splitk_kernel(
    const float* __restrict__ off, const __bf16* __restrict__ xt,
    const __bf16* __restrict__ wfrag, float* __restrict__ out)
{
    __shared__ __align__(16) __bf16 Bt[PX][LDR32];   // 32 x 392 bf16 = 25088 B
    __shared__ __align__(16) uint4 sDesc[96];

    // XCD swizzle: b rides the low bits
    const int bidx = blockIdx.x;     // [0, 1536)
    const int b    = (bidx & 7) >> 1;
    const int sub  = ((bidx >> 3) << 1) | (bidx & 1);   // [0, 384)
    const int kh3  = sub % 3;
    const int rem  = sub / 3;        // [0, 128)
    const int i    = rem >> 1;
    const int j0   = (rem & 1) * PX;
    const int tid  = threadIdx.x;

    const int tap0 = kh3 * 3;
    const int l  = tid & 63;
    const int wv = tid >> 6;            // 0..3 -> 32-o tile

    const __bf16* xtb = xt + (((size_t)b << 12) * CIN);

    // ---- phase 0: 96 descs (3 taps x 32 px) computed inline -> LDS ----
    if (tid < 96) {
        int tt = tid >> 5, p = tid & 31;
        sDesc[tid] = desc_make(off, b, i, j0 + p, tap0 + tt);
    }
    __syncthreads();

    // ---- stage 96 descs, 24 per wave, register-batched quarter-wave gathers ----
    {
        const int q  = l >> 4;
        const int ll = l & 15;
        const __bf16* base = xtb + 8 * ll;

        uint4 qd[6];
        int   pp[6], tt[6];
        #pragma unroll
        for (int m = 0; m < 6; ++m) {
            int dl = wv * 24 + m * 4 + q;    // [0,96)
            tt[m] = dl >> 5;
            pp[m] = dl & 31;
            qd[m] = sDesc[dl];
        }

        #pragma unroll
        for (int h = 0; h < 2; ++h) {
            uint4  v[3][4];
            half4v gh[3];
            #pragma unroll
            for (int m = 0; m < 3; ++m) {
                uint4 qm = qd[h * 3 + m];
                unsigned int zz[2] = { qm.z, qm.w };
                __builtin_memcpy(&gh[m], &zz, 8);
                unsigned short idx[4] = {
                    (unsigned short)(qm.x & 0xffff), (unsigned short)(qm.x >> 16),
                    (unsigned short)(qm.y & 0xffff), (unsigned short)(qm.y >> 16) };
                #pragma unroll
                for (int cr = 0; cr < 4; ++cr)
                    v[m][cr] = *(const uint4*)(base + (size_t)idx[cr] * CIN);
            }
            #pragma unroll
            for (int m = 0; m < 3; ++m) {
                float s[8] = {0.f,0.f,0.f,0.f,0.f,0.f,0.f,0.f};
                #pragma unroll
                for (int cr = 0; cr < 4; ++cr) {
                    float gf = (float)gh[m][cr];
                    unsigned int dw[4] = { v[m][cr].x, v[m][cr].y, v[m][cr].z, v[m][cr].w };
                    #pragma unroll
                    for (int e = 0; e < 4; ++e) {
                        float clo, chi;
                        unsigned int lo = dw[e] << 16, hi = dw[e] & 0xffff0000u;
                        __builtin_memcpy(&clo, &lo, 4);
                        __builtin_memcpy(&chi, &hi, 4);
                        s[2 * e]     += gf * clo;
                        s[2 * e + 1] += gf * chi;
                    }
                }
                v8bf16 pr;
                #pragma unroll
                for (int e = 0; e < 8; ++e) pr[e] = (__bf16)s[e];
                int mm = h * 3 + m;
                *(v8bf16*)&Bt[pp[mm]][tt[mm] * CIN + 8 * ll] = pr;
            }
        }
    }
    __syncthreads();

    // ---- MFMA: wave wv = o-tile [wv*32, wv*32+32) x px [j0, j0+32) ----
    f32x16 acc = {0.f,0.f,0.f,0.f,0.f,0.f,0.f,0.f,0.f,0.f,0.f,0.f,0.f,0.f,0.f,0.f};
    const __bf16* brow = &Bt[l & 31][(l >> 5) * 8];
    const __bf16* warow = wfrag + (((size_t)wv * KS32 + kh3 * KSC32) * 64 + l) * 8;

    #pragma unroll 6
    for (int ks = 0; ks < KSC32; ++ks) {
        v8bf16 afrag = *(const v8bf16*)(warow + (size_t)ks * 64 * 8);
        v8bf16 bfrag = *(const v8bf16*)(brow + ks * 16);
        acc = __builtin_amdgcn_mfma_f32_32x32x16_bf16(afrag, bfrag, acc, 0, 0, 0);
    }

    // ---- epilogue: px = l&31, o = wv*32 + 4*(l>>5) + (reg&3) + 8*(reg>>2) ----
    {
        int obase = wv * 32 + 4 * (l >> 5);
        float* opb = out + (((size_t)(b * OC + obase)) << 12) + (i << 6) + j0 + (l & 31);
        #pragma unroll
        for (int reg = 0; reg < 16; ++reg) {
            int oo = (reg & 3) + 8 * (reg >> 2);
            unsafeAtomicAdd(opb + ((size_t)oo << 12), acc[reg]);
        }
    }
}

// ---------- round-5 fused fallback (verified) ----------
__global__ __launch_bounds__(512, 8) void deform_fused_kernel(
    const float* __restrict__ x, const float* __restrict__ off,
    const float* __restrict__ w, const __bf16* __restrict__ wfrag,
    const __bf16* __restrict__ xt, float* __restrict__ out, int mode)
{
    __shared__ __align__(16) __bf16 Bt[PX][LDBc];
    __shared__ __align__(8)  unsigned short sIdxP[NDESC][4];
    __shared__ __align__(8)  _Float16      sGP[NDESC][4];

    const int bidx = blockIdx.x;
    const int b   = bidx >> 8;
    const int i   = (bidx >> 2) & 63;
    const int j0  = ((bidx >> 1) & 1) * PX;
    const int oh  = bidx & 1;
    const int tid = threadIdx.x;

    if (tid < NDESC) {
        int k = tid >> 5, p = tid & 31;
        int j = j0 + p;
        float ox = off[(((b * 18) + 2 * k) * 64 + i) * 64 + j];
        float oy = off[(((b * 18) + 2 * k + 1) * 64 + i) * 64 + j];
        float px = (float)(i + k / 3) + ox;
        float py = (float)(j + k % 3) + oy;
        float fx = floorf(px), fy = floorf(py);
        int qltx = (int)fminf(fmaxf(fx, 0.f), 65.f);
        int qlty = (int)fminf(fmaxf(fy, 0.f), 65.f);
        int qrbx = (int)fminf(fmaxf(fx + 1.f, 0.f), 65.f);
        int qrby = (int)fminf(fmaxf(fy + 1.f, 0.f), 65.f);
        if (px < 1.f || px > 64.f) px = fx;
        if (py < 1.f || py > 64.f) py = fy;
        px = fminf(fmaxf(px, 0.f), 65.f);
        py = fminf(fmaxf(py, 0.f), 65.f);
        float wxl = 1.f + (float)qltx - px;
        float wxr = 1.f - ((float)qrbx - px);
        float wyl = 1.f + (float)qlty - py;
        float wyr = 1.f - ((float)qrby - py);
        float g[4] = { wxl * wyl, wxr * wyr, wxl * wyr, wxr * wyl };
        int qx[4] = { qltx, qrbx, qltx, qrbx };
        int qy[4] = { qlty, qrby, qrby, qlty };
        #pragma unroll
        for (int cr = 0; cr < 4; ++cr) {
            bool inb = (qx[cr] >= 1) && (qx[cr] <= 64) && (qy[cr] >= 1) && (qy[cr] <= 64);
            sIdxP[tid][cr] = inb ? (unsigned short)((qx[cr] - 1) * 64 + (qy[cr] - 1)) : 0;
            sGP[tid][cr]   = inb ? (_Float16)g[cr] : (_Float16)0.f;
        }
    }
    __syncthreads();

    const int l    = tid & 63;
    const int wv   = tid >> 6;
    const int ot   = oh * 4 + (wv & 3);
    const int ph   = wv >> 2;
    const int quad = l >> 4;
    const int lr   = l & 15;

    f32x4 acc = {0.f, 0.f, 0.f, 0.f};
    const __bf16* xtb = xt + ((size_t)b * 4096) * CIN;
    const float*  xb  = x + ((size_t)b * CIN << 12);
    const __bf16* brow = &Bt[ph * 16 + lr][quad * 8];

    for (int t = 0; t < 3; ++t) {
        if (mode == 2) {
            #pragma unroll 4
            for (int dd = 0; dd < KSC; ++dd) {
                int dl = wv * KSC + dd;
                int tap_l = dl >> 5, p = dl & 31;
                int d = t * 96 + dl;
                ushort4v id = *(const ushort4v*)&sIdxP[d][0];
                half4v   gh = *(const half4v*)&sGP[d][0];
                float s0 = 0.f, s1 = 0.f;
                #pragma unroll
                for (int cr = 0; cr < 4; ++cr) {
                    unsigned int v = *(const unsigned int*)(xtb + (size_t)id[cr] * CIN + 2 * l);
                    float c0v, c1v;
                    unsigned int lo = v << 16, hi = v & 0xffff0000u;
                    __builtin_memcpy(&c0v, &lo, 4);
                    __builtin_memcpy(&c1v, &hi, 4);
                    float gf = (float)gh[cr];
                    s0 += gf * c0v;
                    s1 += gf * c1v;
                }
                bf16x2 pr = { (__bf16)s0, (__bf16)s1 };
                *(bf16x2*)&Bt[p][tap_l * CIN + 2 * l] = pr;
            }
        } else {
            for (int dd = 0; dd < KSC; ++dd) {
                int dl = wv * KSC + dd;
                int tap_l = dl >> 5, p = dl & 31;
                int d = t * 96 + dl;
                ushort4v id = *(const ushort4v*)&sIdxP[d][0];
                half4v   gh = *(const half4v*)&sGP[d][0];
                float s0 = 0.f, s1 = 0.f;
                #pragma unroll
                for (int cr = 0; cr < 4; ++cr) {
                    float gf = (float)gh[cr];
                    s0 += gf * xb[((size_t)(2 * l) << 12) + id[cr]];
                    s1 += gf * xb[((size_t)(2 * l + 1) << 12) + id[cr]];
                }
                bf16x2 pr = { (__bf16)s0, (__bf16)s1 };
                *(bf16x2*)&Bt[p][tap_l * CIN + 2 * l] = pr;
            }
        }
        __syncthreads();

        #pragma unroll 4
        for (int ks = 0; ks < KSC; ++ks) {
            int ks_g = t * KSC + ks;
            v8bf16 bfrag = *(const v8bf16*)(brow + ks * 32);
            v8bf16 afrag;
            if (mode >= 1) {
                afrag = *(const v8bf16*)(wfrag + (((size_t)ot * KSTEPS + ks_g) * 64 + l) * 8);
            } else {
                int o = ot * 16 + lr;
                #pragma unroll
                for (int e = 0; e < 8; ++e) {
                    int k = ks_g * 32 + quad * 8 + e;
                    int tap = k >> 7, c = k & 127;
                    afrag[e] = (__bf16)w[(size_t)o * KTOT + c * NPT + tap];
                }
            }
            acc = __builtin_amdgcn_mfma_f32_16x16x32_bf16(afrag, bfrag, acc, 0, 0, 0);
        }
        if (t < 2) __syncthreads();
    }

    {
        int obase = ot * 16 + quad * 4;
        float* op = out + (((size_t)(b * OC + obase)) << 12) + (i << 6) + j0 + ph * 16 + lr;
        #pragma unroll
        for (int r = 0; r < 4; ++r)
            op[(size_t)r << 12] = acc[r];
    }
}

// standalone prep pieces for fallback modes (old 16x16x32 wfrag layout)
__global__ __launch_bounds__(256) void wfrag_kernel(const float* __restrict__ w,
                                                    __bf16* __restrict__ wfrag) {
    int t = blockIdx.x * 256 + threadIdx.x;
    if (t >= 8 * KSTEPS * 64) return;
    int lane = t & 63;
    int ks   = (t >> 6) % KSTEPS;
    int ot   = t / (KSTEPS * 64);
    int o    = ot * 16 + (lane & 15);
    v8bf16 frag;
    #pragma unroll
    for (int e = 0; e < 8; ++e) {
        int k   = ks * 32 + (lane >> 4) * 8 + e;
        int tap = k >> 7, c = k & 127;
        frag[e] = (__bf16)w[(size_t)o * KTOT + c * NPT + tap];
    }
    *(v8bf16*)(wfrag + (size_t)t * 8) = frag;
}

__global__ __launch_bounds__(256) void xpose_kernel(const float* __restrict__ x,
                                                    __bf16* __restrict__ xt) {
    __shared__ float tile[64][33];
    const int bidx = blockIdx.x;
    const int b   = bidx >> 8;
    const int hw0 = ((bidx >> 2) & 63) * 64;
    const int c0  = (bidx & 3) * 32;
    const int tid = threadIdx.x;
    #pragma unroll
    for (int r = 0; r < 8; ++r) {
        int c_l  = (tid >> 6) + r * 4;
        int hw_l = tid & 63;
        tile[hw_l][c_l] = x[((size_t)(b * CIN + c0 + c_l) << 12) + hw0 + hw_l];
    }
    __syncthreads();
    #pragma unroll
    for (int r = 0; r < 8; ++r) {
        int hw_l = (tid >> 5) + r * 8;
        int c_l  = tid & 31;
        xt[((size_t)(b * 4096 + hw0 + hw_l)) * CIN + c0 + c_l] = (__bf16)tile[hw_l][c_l];
    }
}

extern "C" void kernel_launch(void* const* d_in, const int* in_sizes, int n_in,
                              void* d_out, int out_size, void* d_ws, size_t ws_size,
                              hipStream_t stream) {
    const float* x   = (const float*)d_in[0];
    const float* off = (const float*)d_in[1];
    const float* w   = (const float*)d_in[2];
    float* out = (float*)d_out;

    const size_t wfrag_bytes = (size_t)OC * KTOT * sizeof(__bf16);        // 294912
    const size_t xt_bytes    = (size_t)4 * 4096 * CIN * sizeof(__bf16);   // 4 MB

    int mode = 0;
    if (ws_size >= wfrag_bytes + xt_bytes) mode = 3;
    else if (ws_size >= wfrag_bytes) mode = 1;

    __bf16* wfrag = (__bf16*)d_ws;
    __bf16* xt    = (__bf16*)((char*)d_ws + wfrag_bytes);

    if (mode == 3) {
        prep_kernel<<<PB_TOTAL, 256, 0, stream>>>(x, w, wfrag, xt, out);
        splitk_kernel<<<1536, 256, 0, stream>>>(off, xt, wfrag, out);
    } else {
        if (mode >= 1)
            wfrag_kernel<<<(8 * KSTEPS * 64 + 255) / 256, 256, 0, stream>>>(w, wfrag);
        deform_fused_kernel<<<4 * 64 * 2 * 2, 512, 0, stream>>>(x, off, w, wfrag, xt, out, mode);
    }
}